// Round 1
// 1365.217 us; speedup vs baseline: 1.1903x; 1.1903x over previous
//
#include <hip/hip_runtime.h>
#include <math.h>

#define SIZE_N   (1 << 25)       // 33554432
#define FLATD    30000000
#define FLATD4   7500000         // FLATD / 4 (exact)
#define LOW_N    8192            // 2^13 low-bit FWHT tile
#define HIGH_N   4096            // 2^12 high-bit rows

// ---------------- K1: pad(theta)*B fused with low-13-bit FWHT ----------------
// 512 threads: 4 blocks/CU (128 KB LDS) -> 32 waves/CU.
__global__ __launch_bounds__(512) void k1_padB_fwht_low(const float* __restrict__ theta,
                                                        const float* __restrict__ B,
                                                        float* __restrict__ x) {
    __shared__ float lds[LOW_N];
    float4* lds4 = (float4*)lds;
    const int t   = threadIdx.x;
    const int blk = blockIdx.x;              // 4096 blocks
    const int base4 = blk * (LOW_N / 4);     // float4 index base
    const float4* B4  = (const float4*)B;
    const float4* th4 = (const float4*)theta;

#pragma unroll
    for (int i = 0; i < 4; ++i) {
        int l4 = t + (i << 9);
        int g4 = base4 + l4;
        float4 b = B4[g4];
        float4 v = make_float4(0.f, 0.f, 0.f, 0.f);
        if (g4 < FLATD4) v = th4[g4];
        v.x *= b.x; v.y *= b.y; v.z *= b.z; v.w *= b.w;
        lds4[l4] = v;
    }

    for (int s = 0; s < 13; ++s) {
        __syncthreads();
        int h = 1 << s;
#pragma unroll
        for (int i = 0; i < 8; ++i) {
            int p   = t + (i << 9);                       // pair id 0..4095
            int idx = ((p >> s) << (s + 1)) | (p & (h - 1));
            float a = lds[idx];
            float b2 = lds[idx + h];
            lds[idx]     = a + b2;
            lds[idx + h] = a - b2;
        }
    }
    __syncthreads();

    float4* x4 = (float4*)x;
#pragma unroll
    for (int i = 0; i < 4; ++i) {
        int l4 = t + (i << 9);
        x4[base4 + l4] = lds4[l4];
    }
}

// ---------------- K2: high-12-bit FWHT in place on x ----------------
// view x as [4096 rows][8192 cols]; FWHT over rows. Tile = all rows x 4 cols.
// XCD-chunked swizzle: the 4 blocks sharing each 64B line co-reside on one XCD L2.
__global__ __launch_bounds__(512) void k2_fwht_high(float* __restrict__ x) {
    __shared__ float lds[HIGH_N * 4];        // 64 KB: lds[r*4 + c]
    float4* lds4 = (float4*)lds;
    const int t   = threadIdx.x;
    const int hw  = blockIdx.x;              // 2048 blocks
    const int blk = ((hw & 7) << 8) | (hw >> 3);   // bijective: 2048 = 8 XCDs * 256
    float4* x4 = (float4*)x;

#pragma unroll
    for (int i = 0; i < 8; ++i) {
        int r = t + (i << 9);                // row 0..4095
        lds4[r] = x4[r * 2048 + blk];        // float4 index = (r*8192 + blk*4)/4
    }

    for (int s = 0; s < 12; ++s) {
        __syncthreads();
        int h = 1 << s;
#pragma unroll
        for (int i = 0; i < 16; ++i) {
            int w = t + (i << 9);            // work item 0..8191
            int c = w & 3;
            int p = w >> 2;                  // pair id 0..2047
            int r = ((p >> s) << (s + 1)) | (p & (h - 1));
            int a0 = (r << 2) | c;
            int a1 = ((r + h) << 2) | c;
            float a = lds[a0];
            float b = lds[a1];
            lds[a0] = a + b;
            lds[a1] = a - b;
        }
    }
    __syncthreads();

#pragma unroll
    for (int i = 0; i < 8; ++i) {
        int r = t + (i << 9);
        x4[r * 2048 + blk] = lds4[r];
    }
}

// ---------------- K3: y = x[Pi]*G fused with low-13-bit FWHT ----------------
// 512 threads: 4 blocks/CU -> 32 waves/CU for gather miss-level parallelism.
__global__ __launch_bounds__(512) void k3_gather_fwht_low(const float* __restrict__ x,
                                                          const int* __restrict__ Pi,
                                                          const float* __restrict__ G,
                                                          float* __restrict__ y) {
    __shared__ float lds[LOW_N];
    float4* lds4 = (float4*)lds;
    const int t   = threadIdx.x;
    const int blk = blockIdx.x;              // 4096 blocks
    const int base4 = blk * (LOW_N / 4);
    const int4*   Pi4 = (const int4*)Pi;
    const float4* G4  = (const float4*)G;

#pragma unroll
    for (int i = 0; i < 4; ++i) {
        int l4 = t + (i << 9);
        int g4 = base4 + l4;
        int4   p4 = Pi4[g4];
        float4 g  = G4[g4];
        float4 v;
        v.x = x[p4.x] * g.x;
        v.y = x[p4.y] * g.y;
        v.z = x[p4.z] * g.z;
        v.w = x[p4.w] * g.w;
        lds4[l4] = v;
    }

    for (int s = 0; s < 13; ++s) {
        __syncthreads();
        int h = 1 << s;
#pragma unroll
        for (int i = 0; i < 8; ++i) {
            int p   = t + (i << 9);
            int idx = ((p >> s) << (s + 1)) | (p & (h - 1));
            float a = lds[idx];
            float b2 = lds[idx + h];
            lds[idx]     = a + b2;
            lds[idx + h] = a - b2;
        }
    }
    __syncthreads();

    float4* y4 = (float4*)y;
#pragma unroll
    for (int i = 0; i < 4; ++i) {
        int l4 = t + (i << 9);
        y4[base4 + l4] = lds4[l4];
    }
}

// ---------------- K4: high-12-bit FWHT on y fused with truncate + scale ----------------
__global__ __launch_bounds__(512) void k4_fwht_high_out(const float* __restrict__ y,
                                                        const float* __restrict__ divisor,
                                                        float* __restrict__ out) {
    __shared__ float lds[HIGH_N * 4];
    float4* lds4 = (float4*)lds;
    const int t   = threadIdx.x;
    const int hw  = blockIdx.x;              // 2048 blocks
    const int blk = ((hw & 7) << 8) | (hw >> 3);   // XCD-chunked swizzle
    const float4* y4 = (const float4*)y;

#pragma unroll
    for (int i = 0; i < 8; ++i) {
        int r = t + (i << 9);
        lds4[r] = y4[r * 2048 + blk];
    }

    const float scale = divisor[0] * sqrtf((float)FLATD / (float)SIZE_N);
    const float inv   = 1.0f / scale;

    for (int s = 0; s < 12; ++s) {
        __syncthreads();
        int h = 1 << s;
#pragma unroll
        for (int i = 0; i < 16; ++i) {
            int w = t + (i << 9);
            int c = w & 3;
            int p = w >> 2;
            int r = ((p >> s) << (s + 1)) | (p & (h - 1));
            int a0 = (r << 2) | c;
            int a1 = ((r + h) << 2) | c;
            float a = lds[a0];
            float b = lds[a1];
            lds[a0] = a + b;
            lds[a1] = a - b;
        }
    }
    __syncthreads();

    float4* out4 = (float4*)out;
#pragma unroll
    for (int i = 0; i < 8; ++i) {
        int r  = t + (i << 9);
        int o4 = r * 2048 + blk;             // float4 index in element space
        if (o4 < FLATD4) {
            float4 v = lds4[r];
            v.x *= inv; v.y *= inv; v.z *= inv; v.w *= inv;
            out4[o4] = v;
        }
    }
}

extern "C" void kernel_launch(void* const* d_in, const int* in_sizes, int n_in,
                              void* d_out, int out_size, void* d_ws, size_t ws_size,
                              hipStream_t stream) {
    const float* theta   = (const float*)d_in[0];
    const float* G       = (const float*)d_in[1];
    const float* B       = (const float*)d_in[2];
    const float* divisor = (const float*)d_in[3];
    const int*   Pi      = (const int*)d_in[4];
    float* out = (float*)d_out;

    float* x = (float*)d_ws;                 // SIZE_N floats (134 MB)
    float* y = x + SIZE_N;                   // SIZE_N floats (134 MB)

    k1_padB_fwht_low<<<SIZE_N / LOW_N, 512, 0, stream>>>(theta, B, x);
    k2_fwht_high<<<LOW_N / 4, 512, 0, stream>>>(x);
    k3_gather_fwht_low<<<SIZE_N / LOW_N, 512, 0, stream>>>(x, Pi, G, y);
    k4_fwht_high_out<<<LOW_N / 4, 512, 0, stream>>>(y, divisor, out);
}

// Round 2
// 1306.383 us; speedup vs baseline: 1.2439x; 1.0450x over previous
//
#include <hip/hip_runtime.h>
#include <math.h>

#define SIZE_N   (1 << 25)       // 33554432
#define FLATD    30000000
#define FLATD4   7500000         // FLATD / 4 (exact)
#define LOW_N    8192            // 2^13 low-bit FWHT tile

// ---------------- K1: pad(theta)*B fused with low-13-bit FWHT ----------------
// 512 threads: 4 blocks/CU (128 KB LDS) -> 32 waves/CU.
__global__ __launch_bounds__(512) void k1_padB_fwht_low(const float* __restrict__ theta,
                                                        const float* __restrict__ B,
                                                        float* __restrict__ x) {
    __shared__ float lds[LOW_N];
    float4* lds4 = (float4*)lds;
    const int t   = threadIdx.x;
    const int blk = blockIdx.x;              // 4096 blocks
    const int base4 = blk * (LOW_N / 4);     // float4 index base
    const float4* B4  = (const float4*)B;
    const float4* th4 = (const float4*)theta;

#pragma unroll
    for (int i = 0; i < 4; ++i) {
        int l4 = t + (i << 9);
        int g4 = base4 + l4;
        float4 b = B4[g4];
        float4 v = make_float4(0.f, 0.f, 0.f, 0.f);
        if (g4 < FLATD4) v = th4[g4];
        v.x *= b.x; v.y *= b.y; v.z *= b.z; v.w *= b.w;
        lds4[l4] = v;
    }

    for (int s = 0; s < 13; ++s) {
        __syncthreads();
        int h = 1 << s;
#pragma unroll
        for (int i = 0; i < 8; ++i) {
            int p   = t + (i << 9);                       // pair id 0..4095
            int idx = ((p >> s) << (s + 1)) | (p & (h - 1));
            float a = lds[idx];
            float b2 = lds[idx + h];
            lds[idx]     = a + b2;
            lds[idx + h] = a - b2;
        }
    }
    __syncthreads();

    float4* x4 = (float4*)x;
#pragma unroll
    for (int i = 0; i < 4; ++i) {
        int l4 = t + (i << 9);
        x4[base4 + l4] = lds4[l4];
    }
}

// ---------------- K2a/K2b/K4a: 6-bit FWHT stage, fully coalesced ----------------
// Tile = [64 rows][256 contiguous floats] = 64 KB LDS. Every global access is a
// 1 KB contiguous run (full 64B lines, no line splitting, no inter-block sharing).
//   stage A (bits 13-18): A4 = 131072 (2^19 floats /4), R4 = 2048  (8192 floats /4)
//   stage B (bits 19-24): A4 = 2048,                    R4 = 131072
// Butterfly order: s=0..5 over rows == global bits in increasing order ->
// identical pairing + arithmetic to the previous 12-stage kernel (bit-exact).
__global__ __launch_bounds__(512) void k_high6(float* __restrict__ x, int A4, int R4) {
    __shared__ float lds[64 * 256];          // 64 KB
    float4* lds4 = (float4*)lds;
    const int t   = threadIdx.x;
    const int blk = blockIdx.x;              // 2048 blocks = 64 outer x 32 lo-chunks
    const int base4 = (blk >> 5) * A4 + (blk & 31) * 64;
    float4* x4 = (float4*)x;

#pragma unroll
    for (int i = 0; i < 8; ++i) {
        int idx = t + (i << 9);              // 0..4095 float4 slots
        int row = idx >> 6;                  // 0..63
        int l4  = idx & 63;                  // 0..63 float4 within row
        lds4[idx] = x4[base4 + row * R4 + l4];
    }

    for (int s = 0; s < 6; ++s) {
        __syncthreads();
        int h = 1 << s;
#pragma unroll
        for (int i = 0; i < 4; ++i) {
            int w  = t + (i << 9);           // 0..2047
            int p  = w >> 6;                 // row-pair id 0..31
            int l4 = w & 63;
            int r0 = ((p >> s) << (s + 1)) | (p & (h - 1));
            int a0 = (r0 << 6) | l4;
            int a1 = ((r0 + h) << 6) | l4;
            float4 a = lds4[a0];
            float4 b = lds4[a1];
            lds4[a0] = make_float4(a.x + b.x, a.y + b.y, a.z + b.z, a.w + b.w);
            lds4[a1] = make_float4(a.x - b.x, a.y - b.y, a.z - b.z, a.w - b.w);
        }
    }
    __syncthreads();

#pragma unroll
    for (int i = 0; i < 8; ++i) {
        int idx = t + (i << 9);
        int row = idx >> 6;
        int l4  = idx & 63;
        x4[base4 + row * R4 + l4] = lds4[idx];
    }
}

// ---------------- K4b: final 6-bit stage (bits 19-24) + truncate + scale ----------------
__global__ __launch_bounds__(512) void k_high6_out(const float* __restrict__ y,
                                                   const float* __restrict__ divisor,
                                                   float* __restrict__ out) {
    __shared__ float lds[64 * 256];
    float4* lds4 = (float4*)lds;
    const int t   = threadIdx.x;
    const int blk = blockIdx.x;              // 2048 blocks
    const int base4 = (blk >> 5) * 2048 + (blk & 31) * 64;   // A4=2048 (mid fixed)
    const float4* y4 = (const float4*)y;

#pragma unroll
    for (int i = 0; i < 8; ++i) {
        int idx = t + (i << 9);
        int row = idx >> 6;                  // top bits 19-24
        int l4  = idx & 63;
        lds4[idx] = y4[base4 + row * 131072 + l4];
    }

    const float scale = divisor[0] * sqrtf((float)FLATD / (float)SIZE_N);
    const float inv   = 1.0f / scale;

    for (int s = 0; s < 6; ++s) {
        __syncthreads();
        int h = 1 << s;
#pragma unroll
        for (int i = 0; i < 4; ++i) {
            int w  = t + (i << 9);
            int p  = w >> 6;
            int l4 = w & 63;
            int r0 = ((p >> s) << (s + 1)) | (p & (h - 1));
            int a0 = (r0 << 6) | l4;
            int a1 = ((r0 + h) << 6) | l4;
            float4 a = lds4[a0];
            float4 b = lds4[a1];
            lds4[a0] = make_float4(a.x + b.x, a.y + b.y, a.z + b.z, a.w + b.w);
            lds4[a1] = make_float4(a.x - b.x, a.y - b.y, a.z - b.z, a.w - b.w);
        }
    }
    __syncthreads();

    float4* out4 = (float4*)out;
#pragma unroll
    for (int i = 0; i < 8; ++i) {
        int idx = t + (i << 9);
        int row = idx >> 6;
        int l4  = idx & 63;
        int o4  = base4 + row * 131072 + l4;
        if (o4 < FLATD4) {
            float4 v = lds4[idx];
            v.x *= inv; v.y *= inv; v.z *= inv; v.w *= inv;
            out4[o4] = v;
        }
    }
}

// ---------------- K3: y = x[Pi]*G fused with low-13-bit FWHT ----------------
// Throughput-bound on random 64B-line fetch (~3.5 TB/s ceiling) — unchanged this round.
__global__ __launch_bounds__(512) void k3_gather_fwht_low(const float* __restrict__ x,
                                                          const int* __restrict__ Pi,
                                                          const float* __restrict__ G,
                                                          float* __restrict__ y) {
    __shared__ float lds[LOW_N];
    float4* lds4 = (float4*)lds;
    const int t   = threadIdx.x;
    const int blk = blockIdx.x;              // 4096 blocks
    const int base4 = blk * (LOW_N / 4);
    const int4*   Pi4 = (const int4*)Pi;
    const float4* G4  = (const float4*)G;

#pragma unroll
    for (int i = 0; i < 4; ++i) {
        int l4 = t + (i << 9);
        int g4 = base4 + l4;
        int4   p4 = Pi4[g4];
        float4 g  = G4[g4];
        float4 v;
        v.x = x[p4.x] * g.x;
        v.y = x[p4.y] * g.y;
        v.z = x[p4.z] * g.z;
        v.w = x[p4.w] * g.w;
        lds4[l4] = v;
    }

    for (int s = 0; s < 13; ++s) {
        __syncthreads();
        int h = 1 << s;
#pragma unroll
        for (int i = 0; i < 8; ++i) {
            int p   = t + (i << 9);
            int idx = ((p >> s) << (s + 1)) | (p & (h - 1));
            float a = lds[idx];
            float b2 = lds[idx + h];
            lds[idx]     = a + b2;
            lds[idx + h] = a - b2;
        }
    }
    __syncthreads();

    float4* y4 = (float4*)y;
#pragma unroll
    for (int i = 0; i < 4; ++i) {
        int l4 = t + (i << 9);
        y4[base4 + l4] = lds4[l4];
    }
}

extern "C" void kernel_launch(void* const* d_in, const int* in_sizes, int n_in,
                              void* d_out, int out_size, void* d_ws, size_t ws_size,
                              hipStream_t stream) {
    const float* theta   = (const float*)d_in[0];
    const float* G       = (const float*)d_in[1];
    const float* B       = (const float*)d_in[2];
    const float* divisor = (const float*)d_in[3];
    const int*   Pi      = (const int*)d_in[4];
    float* out = (float*)d_out;

    float* x = (float*)d_ws;                 // SIZE_N floats (134 MB)
    float* y = x + SIZE_N;                   // SIZE_N floats (134 MB)

    k1_padB_fwht_low<<<SIZE_N / LOW_N, 512, 0, stream>>>(theta, B, x);
    k_high6<<<2048, 512, 0, stream>>>(x, 131072, 2048);    // bits 13-18
    k_high6<<<2048, 512, 0, stream>>>(x, 2048, 131072);    // bits 19-24
    k3_gather_fwht_low<<<SIZE_N / LOW_N, 512, 0, stream>>>(x, Pi, G, y);
    k_high6<<<2048, 512, 0, stream>>>(y, 131072, 2048);    // bits 13-18
    k_high6_out<<<2048, 512, 0, stream>>>(y, divisor, out); // bits 19-24 + trunc/scale
}

// Round 3
// 1270.484 us; speedup vs baseline: 1.2791x; 1.0283x over previous
//
#include <hip/hip_runtime.h>
#include <math.h>

#define SIZE_N   (1 << 25)       // 33554432
#define FLATD    30000000
#define FLATD4   7500000         // FLATD / 4 (exact)
#define LOW_N    8192            // 2^13 low-bit FWHT tile

// Index fields of element e (25 bits): top(6) = bits 19-24, mid(6) = bits 13-18,
// low(13) = bits 0-12 split as lc(5) = bits 8-12, li(8) = bits 0-7.
// Layouts (float4 indices, li4 = li/4 in 0..63):
//   standard: top*131072 + mid*2048 + lc*64   + li4
//   z:        top*131072 + lc*4096  + mid*64  + li4   (consumer P_mid reads contiguous)
//   w:        mid*131072 + lc*4096  + top*64  + li4   (consumer P_top reads contiguous)
// Every kernel READS contiguous per block; strided-ness lives on the WRITE side
// (1 KB runs, fire-and-forget, L2-absorbed).

// ---------------- shared 6-stage row butterfly on a [64 rows][64 float4] LDS tile ----------------
__device__ __forceinline__ void fwht6_rows(float4* lds4, int t) {
    for (int s = 0; s < 6; ++s) {
        __syncthreads();
        int h = 1 << s;
#pragma unroll
        for (int i = 0; i < 4; ++i) {
            int w  = t + (i << 9);           // 0..2047 work items
            int p  = w >> 6;                 // row-pair id 0..31
            int l4 = w & 63;
            int r0 = ((p >> s) << (s + 1)) | (p & (h - 1));
            int a0 = (r0 << 6) | l4;
            int a1 = ((r0 + h) << 6) | l4;
            float4 a = lds4[a0];
            float4 b = lds4[a1];
            lds4[a0] = make_float4(a.x + b.x, a.y + b.y, a.z + b.z, a.w + b.w);
            lds4[a1] = make_float4(a.x - b.x, a.y - b.y, a.z - b.z, a.w - b.w);
        }
    }
    __syncthreads();
}

// ---------------- K1: pad(theta)*B + low-13 FWHT, write z-layout ----------------
__global__ __launch_bounds__(512) void k1_padB_fwht_low(const float* __restrict__ theta,
                                                        const float* __restrict__ B,
                                                        float* __restrict__ z) {
    __shared__ float lds[LOW_N];
    float4* lds4 = (float4*)lds;
    const int t   = threadIdx.x;
    const int blk = blockIdx.x;              // 4096 chunks: top = blk>>6, mid = blk&63
    const int base4 = blk * 2048;
    const float4* B4  = (const float4*)B;
    const float4* th4 = (const float4*)theta;

#pragma unroll
    for (int i = 0; i < 4; ++i) {
        int l4 = t + (i << 9);
        int g4 = base4 + l4;
        float4 b = B4[g4];
        float4 v = make_float4(0.f, 0.f, 0.f, 0.f);
        if (g4 < FLATD4) v = th4[g4];
        v.x *= b.x; v.y *= b.y; v.z *= b.z; v.w *= b.w;
        lds4[l4] = v;
    }

    for (int s = 0; s < 13; ++s) {
        __syncthreads();
        int h = 1 << s;
#pragma unroll
        for (int i = 0; i < 8; ++i) {
            int p   = t + (i << 9);
            int idx = ((p >> s) << (s + 1)) | (p & (h - 1));
            float a = lds[idx];
            float b2 = lds[idx + h];
            lds[idx]     = a + b2;
            lds[idx + h] = a - b2;
        }
    }
    __syncthreads();

    // write z-layout: 32 runs of 1 KB at 64 KB stride
    float4* z4 = (float4*)z;
    const int top = blk >> 6, mid = blk & 63;
    const int wbase = top * 131072 + mid * 64;
#pragma unroll
    for (int i = 0; i < 4; ++i) {
        int l4  = t + (i << 9);
        int lc  = l4 >> 6, li4 = l4 & 63;
        z4[wbase + lc * 4096 + li4] = lds4[l4];
    }
}

// ---------------- P_mid: butterfly orig bits 13-18. read z contiguous, write w ----------------
__global__ __launch_bounds__(512) void p_mid(const float4* __restrict__ in4,
                                             float4* __restrict__ out4) {
    __shared__ float lds[64 * 256];          // 64 KB tile [mid][li4]
    float4* lds4 = (float4*)lds;
    const int t   = threadIdx.x;
    const int blk = blockIdx.x;              // 2048: top = blk>>5, lc = blk&31
    const int top = blk >> 5, lc = blk & 31;
    const int rbase = (top * 32 + lc) * 4096;

#pragma unroll
    for (int i = 0; i < 8; ++i) {
        int idx = t + (i << 9);
        lds4[idx] = in4[rbase + idx];        // fully contiguous 64 KB
    }

    fwht6_rows(lds4, t);                     // rows = mid (orig bits 13..18, in order)

    const int wb = lc * 4096 + top * 64;
#pragma unroll
    for (int i = 0; i < 8; ++i) {
        int idx = t + (i << 9);
        int mid = idx >> 6, li4 = idx & 63;
        out4[mid * 131072 + wb + li4] = lds4[idx];   // 1 KB runs, 512 KB stride
    }
}

// ---------------- P_top: butterfly orig bits 19-24. read w contiguous, write standard ----------------
__global__ __launch_bounds__(512) void p_top(const float4* __restrict__ in4,
                                             float4* __restrict__ out4) {
    __shared__ float lds[64 * 256];          // tile [top][li4]
    float4* lds4 = (float4*)lds;
    const int t   = threadIdx.x;
    const int blk = blockIdx.x;              // 2048: mid = blk>>5, lc = blk&31
    const int mid = blk >> 5, lc = blk & 31;
    const int rbase = (mid * 32 + lc) * 4096;

#pragma unroll
    for (int i = 0; i < 8; ++i) {
        int idx = t + (i << 9);
        lds4[idx] = in4[rbase + idx];
    }

    fwht6_rows(lds4, t);                     // rows = top (orig bits 19..24, in order)

    const int wb = mid * 2048 + lc * 64;
#pragma unroll
    for (int i = 0; i < 8; ++i) {
        int idx = t + (i << 9);
        int top = idx >> 6, li4 = idx & 63;
        out4[top * 131072 + wb + li4] = lds4[idx];   // standard layout, 1 KB runs
    }
}

// ---------------- P_top_out: P_top + truncate + scale into out ----------------
__global__ __launch_bounds__(512) void p_top_out(const float4* __restrict__ in4,
                                                 const float* __restrict__ divisor,
                                                 float* __restrict__ out) {
    __shared__ float lds[64 * 256];
    float4* lds4 = (float4*)lds;
    const int t   = threadIdx.x;
    const int blk = blockIdx.x;              // 2048: mid = blk>>5, lc = blk&31
    const int mid = blk >> 5, lc = blk & 31;
    const int rbase = (mid * 32 + lc) * 4096;

#pragma unroll
    for (int i = 0; i < 8; ++i) {
        int idx = t + (i << 9);
        lds4[idx] = in4[rbase + idx];
    }

    const float scale = divisor[0] * sqrtf((float)FLATD / (float)SIZE_N);
    const float inv   = 1.0f / scale;

    fwht6_rows(lds4, t);

    float4* out4 = (float4*)out;
    const int wb = mid * 2048 + lc * 64;
#pragma unroll
    for (int i = 0; i < 8; ++i) {
        int idx = t + (i << 9);
        int top = idx >> 6, li4 = idx & 63;
        int o4  = top * 131072 + wb + li4;
        if (o4 < FLATD4) {
            float4 v = lds4[idx];
            v.x *= inv; v.y *= inv; v.z *= inv; v.w *= inv;
            out4[o4] = v;
        }
    }
}

// ---------------- K3: y = x[Pi]*G + low-13 FWHT, write z-layout ----------------
// Fetch-bound on random 64B lines (~3.5 TB/s floor); write remap is hidden.
__global__ __launch_bounds__(512) void k3_gather_fwht_low(const float* __restrict__ x,
                                                          const int* __restrict__ Pi,
                                                          const float* __restrict__ G,
                                                          float* __restrict__ y) {
    __shared__ float lds[LOW_N];
    float4* lds4 = (float4*)lds;
    const int t   = threadIdx.x;
    const int blk = blockIdx.x;              // 4096 dest chunks
    const int base4 = blk * 2048;
    const int4*   Pi4 = (const int4*)Pi;
    const float4* G4  = (const float4*)G;

#pragma unroll
    for (int i = 0; i < 4; ++i) {
        int l4 = t + (i << 9);
        int g4 = base4 + l4;
        int4   p4 = Pi4[g4];
        float4 g  = G4[g4];
        float4 v;
        v.x = x[p4.x] * g.x;
        v.y = x[p4.y] * g.y;
        v.z = x[p4.z] * g.z;
        v.w = x[p4.w] * g.w;
        lds4[l4] = v;
    }

    for (int s = 0; s < 13; ++s) {
        __syncthreads();
        int h = 1 << s;
#pragma unroll
        for (int i = 0; i < 8; ++i) {
            int p   = t + (i << 9);
            int idx = ((p >> s) << (s + 1)) | (p & (h - 1));
            float a = lds[idx];
            float b2 = lds[idx + h];
            lds[idx]     = a + b2;
            lds[idx + h] = a - b2;
        }
    }
    __syncthreads();

    float4* y4 = (float4*)y;
    const int top = blk >> 6, mid = blk & 63;
    const int wbase = top * 131072 + mid * 64;
#pragma unroll
    for (int i = 0; i < 4; ++i) {
        int l4  = t + (i << 9);
        int lc  = l4 >> 6, li4 = l4 & 63;
        y4[wbase + lc * 4096 + li4] = lds4[l4];
    }
}

extern "C" void kernel_launch(void* const* d_in, const int* in_sizes, int n_in,
                              void* d_out, int out_size, void* d_ws, size_t ws_size,
                              hipStream_t stream) {
    const float* theta   = (const float*)d_in[0];
    const float* G       = (const float*)d_in[1];
    const float* B       = (const float*)d_in[2];
    const float* divisor = (const float*)d_in[3];
    const int*   Pi      = (const int*)d_in[4];
    float* out = (float*)d_out;

    float* bufA = (float*)d_ws;              // SIZE_N floats (134 MB)
    float* bufB = bufA + SIZE_N;             // SIZE_N floats (134 MB)
    float4* A4 = (float4*)bufA;
    float4* B4w = (float4*)bufB;

    k1_padB_fwht_low<<<4096, 512, 0, stream>>>(theta, B, bufA);      // -> z
    p_mid<<<2048, 512, 0, stream>>>(A4, B4w);                        // z -> w   (bits 13-18)
    p_top<<<2048, 512, 0, stream>>>(B4w, A4);                        // w -> std (bits 19-24)
    k3_gather_fwht_low<<<4096, 512, 0, stream>>>(bufA, Pi, G, bufB); // std -> y_z
    p_mid<<<2048, 512, 0, stream>>>(B4w, A4);                        // y_z -> y_w (bits 13-18)
    p_top_out<<<2048, 512, 0, stream>>>(A4, divisor, out);           // y_w -> out (bits 19-24)
}